// Round 15
// baseline (260.966 us; speedup 1.0000x reference)
//
#include <hip/hip_runtime.h>
#include <hip/hip_bf16.h>

typedef __bf16 bf16_t;
typedef __bf16 bf16x8 __attribute__((ext_vector_type(8)));
typedef float f32x4 __attribute__((ext_vector_type(4)));

#define SEQ_L 8192
#define DMODEL 1024
#define NHEAD 16
#define HDIM 64
static constexpr int MROWS = 2 * SEQ_L;  // B*L = 16384

// ---------------- async global->LDS (16B per lane) ----------------
__device__ __forceinline__ void async_cp16(const void* g, bf16_t* l) {
  __builtin_amdgcn_global_load_lds(
      (__attribute__((address_space(1))) void*)(void*)(g),
      (__attribute__((address_space(3))) void*)(void*)(l), 16, 0, 0);
}
// Raw barrier: does NOT drain vmcnt/lgkmcnt (waits are placed by hand).
__device__ __forceinline__ void wg_barrier() { __builtin_amdgcn_s_barrier(); }

// ---------------- f32 -> bf16 convert (vectorized) ----------------
__global__ __launch_bounds__(256) void f32_to_bf16_k(const float* __restrict__ in,
                                                     bf16_t* __restrict__ out, int n) {
  int i = (blockIdx.x * 256 + threadIdx.x) * 8;
  if (i >= n) return;
  float4 a = *(const float4*)(in + i);
  float4 b = *(const float4*)(in + i + 4);
  bf16x8 o;
  o[0] = (__bf16)a.x; o[1] = (__bf16)a.y; o[2] = (__bf16)a.z; o[3] = (__bf16)a.w;
  o[4] = (__bf16)b.x; o[5] = (__bf16)b.y; o[6] = (__bf16)b.z; o[7] = (__bf16)b.w;
  *(bf16x8*)(out + i) = o;
}

// ---------------- W (K x N f32) -> Wt (N x K bf16) ----------------
__global__ __launch_bounds__(256) void w_to_bt_k(
    const float* __restrict__ W0, const float* __restrict__ W1,
    const float* __restrict__ W2, const float* __restrict__ W3,
    bf16_t* __restrict__ T0, bf16_t* __restrict__ T1,
    bf16_t* __restrict__ T2, bf16_t* __restrict__ T3) {
  __shared__ float tile[32][33];
  const int z = blockIdx.z;
  const float* W = (z == 0) ? W0 : (z == 1) ? W1 : (z == 2) ? W2 : W3;
  bf16_t* T = (z == 0) ? T0 : (z == 1) ? T1 : (z == 2) ? T2 : T3;
  const int bx = blockIdx.x, by = blockIdx.y;
  const int tx = threadIdx.x, ty = threadIdx.y;  // 32 x 8
#pragma unroll
  for (int r = 0; r < 4; ++r)
    tile[ty + r * 8][tx] = W[(size_t)(by * 32 + ty + r * 8) * DMODEL + bx * 32 + tx];
  __syncthreads();
#pragma unroll
  for (int r = 0; r < 4; ++r)
    T[(size_t)(bx * 32 + ty + r * 8) * DMODEL + by * 32 + tx] = (bf16_t)tile[tx][ty + r * 8];
}

// ---------------- RoPE cos/sin table: tab[pos*32 + j] ----------------
__global__ __launch_bounds__(256) void rope_tab_k(float2* __restrict__ tab) {
  int i = blockIdx.x * 256 + threadIdx.x;  // pos*32 + j
  int pos = i >> 5, j = i & 31;
  double freq = pow(10000.0, -(double)j / 32.0);
  double ang = (double)pos * freq;
  tab[i] = make_float2((float)cos(ang), (float)sin(ang));
}

// -- 128x128 bf16 GEMM, BK=64 DOUBLE-buffered, 2 blocks/CU anti-phase (R15) --
// C(M x N) = A(M x K) @ Bt(N x K)^T + bias, K=1024, 4 waves (2M x 2N),
// per-wave 64x64 (acc[4][4] = 64 AGPR; ~124 combined regs).
// vs R7 (single-buffer, 115.5 us QKV): stage(m+1) -> ALTERNATE buffer issued at
// the TOP of compute(m), so the vmcnt(0) at tile end has issue-to-wait distance
// = full compute span (~1200 cyc >> latency) instead of ~0.  One barrier per
// tile instead of two.  LDS 2 x 32 KB = 64 KB -> 2 blocks/CU anti-phase.
// WAR ledger: stage(m+1) writes buf[(m+1)&1], last READ in tile m-1 whose end
// barrier all waves passed; reads of buf[m&1] are consumed by MFMA (compiler
// lgkmcnt) before tile m's end barrier; stage(m+2) issues after that barrier.
// Swizzle (R7, measured 0-conflict): bf16 row 128B = 8 chunks; physical chunk
// = logical ^ (row&7); read applies XOR; write pre-swizzles the GLOBAL source
// chunk, LDS dest linear (global_load_lds requirement).
// MODE 0: fused QKV (N=3072), bias per range, RoPE on q/k, bf16 outs (stride 1024).
// MODE 1: f32 out + bias (O projection, N=1024).
template <int MODE>
__global__ __launch_bounds__(256, 4) void gemm128(
    const bf16_t* __restrict__ A, const bf16_t* __restrict__ Bt,
    const float* __restrict__ b0, const float* __restrict__ b1,
    const float* __restrict__ b2, const float2* __restrict__ rope,
    void* __restrict__ O0, void* __restrict__ O1, void* __restrict__ O2) {
  constexpr int K = DMODEL;   // 1024
  constexpr int KT = K / 64;  // 16 K-tiles (BK=64)
  __shared__ bf16_t As_[2][128 * 64];  // 2 x 16 KB
  __shared__ bf16_t Bs_[2][128 * 64];  // 2 x 16 KB
  const int tid = threadIdx.x;
  const int lane = tid & 63;
  const int wave = tid >> 6;  // 0..3
  const int wm = wave >> 1;   // 0..1 (64-row half)
  const int wn = wave & 1;    // 0..1 (64-col half)
  const size_t row0 = (size_t)blockIdx.x * 128;
  const int col0 = blockIdx.y * 128;
  const int fr = lane & 15;
  const int g4 = lane >> 4;  // 16B k-chunk group (0..3)

  // staging: wave w covers rows w*32 + (lane>>3) + {0,8,16,24}; chunk pre-swz
  const int srow = lane >> 3;            // 0..7
  const int sch = (lane & 7) ^ srow;     // source chunk = phys ^ (row&7)
  const bf16_t* gA = A + (row0 + wave * 32 + srow) * K + sch * 8;
  const bf16_t* gB = Bt + ((size_t)col0 + wave * 32 + srow) * K + sch * 8;

#define VMCNT(n) asm volatile("s_waitcnt vmcnt(" #n ")")
#define SCHED_FENCE() __builtin_amdgcn_sched_barrier(0)
#define STAGE(j, buf)                                                     \
  do {                                                                    \
    bf16_t* lA = &As_[buf][wave * 2048 + lane * 8];                       \
    bf16_t* lB = &Bs_[buf][wave * 2048 + lane * 8];                       \
    async_cp16(gA + (j)*64, lA);                                          \
    async_cp16(gA + 8 * K + (j)*64, lA + 512);                            \
    async_cp16(gA + 16 * K + (j)*64, lA + 1024);                          \
    async_cp16(gA + 24 * K + (j)*64, lA + 1536);                          \
    async_cp16(gB + (j)*64, lB);                                          \
    async_cp16(gB + 8 * K + (j)*64, lB + 512);                            \
    async_cp16(gB + 16 * K + (j)*64, lB + 1024);                          \
    async_cp16(gB + 24 * K + (j)*64, lB + 1536);                          \
  } while (0)
#define RD(base, row, h)                                                  \
  (*(const bf16x8*)((const char*)(base) + (size_t)(row)*128 +             \
                    ((((h)*4 + g4) ^ ((row)&7)) << 4)))

  f32x4 acc[4][4] = {};
  bf16x8 a4[4], b4[4];

#define KSTEP(CUR, DO_STAGE, JNEXT)                                            \
  do {                                                                         \
    if (DO_STAGE) STAGE(JNEXT, (CUR) ^ 1); /* prefetch, full-tile distance */  \
    _Pragma("unroll") for (int h = 0; h < 2; ++h) {                            \
      _Pragma("unroll") for (int f = 0; f < 4; ++f)                            \
          a4[f] = RD(As_[CUR], wm * 64 + f * 16 + fr, h);                      \
      _Pragma("unroll") for (int n = 0; n < 4; ++n)                            \
          b4[n] = RD(Bs_[CUR], wn * 64 + n * 16 + fr, h);                      \
      __builtin_amdgcn_s_setprio(1);                                           \
      _Pragma("unroll") for (int f = 0; f < 4; ++f)                            \
          _Pragma("unroll") for (int n = 0; n < 4; ++n)                        \
              acc[f][n] = __builtin_amdgcn_mfma_f32_16x16x32_bf16(             \
                  a4[f], b4[n], acc[f][n], 0, 0, 0);                           \
      __builtin_amdgcn_s_setprio(0);                                           \
    }                                                                          \
    VMCNT(0);      /* prefetch landed; satisfied ~free (issued a tile ago) */  \
    wg_barrier();  /* reads of buf[CUR] done + prefetch visible to all */      \
    SCHED_FENCE();                                                             \
  } while (0)

  // prologue: stage tile 0 into buf0
  STAGE(0, 0);
  VMCNT(0);
  wg_barrier();
  SCHED_FENCE();

#pragma unroll 1
  for (int mm = 0; mm < KT / 2; ++mm) {
    KSTEP(0, true, 2 * mm + 1);                 // compute buf0, stage ->buf1
    KSTEP(1, (mm < KT / 2 - 1), 2 * mm + 2);    // compute buf1, stage ->buf0
  }
#undef KSTEP
#undef STAGE
#undef RD
#undef VMCNT
#undef SCHED_FENCE

  // ---- epilogue. C/D layout: col = lane&15, row = (lane>>4)*4 + reg ----
  const int lr = g4 * 4;
  const int lc = lane & 15;
  const int gcol = col0 + wn * 64;  // aligned to one head (64)
  int which = 0;
  const float* bias = b0;
  int ocol = gcol;
  if constexpr (MODE == 0) {
    which = gcol >> 10;
    bias = (which == 0) ? b0 : (which == 1) ? b1 : b2;
    ocol = gcol - (which << 10);
  }
  const bool do_rope = (MODE == 0) && (which < 2);
  bf16_t* Cb = nullptr;
  float* Cf = nullptr;
  if constexpr (MODE == 0)
    Cb = (bf16_t*)((which == 0) ? O0 : (which == 1) ? O1 : O2);
  else
    Cf = (float*)O0;

#pragma unroll
  for (int mf = 0; mf < 4; ++mf) {
#pragma unroll
    for (int i = 0; i < 4; ++i) {
      const size_t grow = row0 + wm * 64 + mf * 16 + lr + i;
      float vv[4];
#pragma unroll
      for (int n = 0; n < 4; ++n) vv[n] = acc[mf][n][i] + bias[ocol + n * 16 + lc];
      if (do_rope) {
        // d(in-head) = n*16+lc; j = d>>1; partner d<32 ? d+32 (-sin) : d-32 (+sin)
        const int pos = (int)(grow & (size_t)(SEQ_L - 1));
        const float2* rp = rope + (size_t)pos * 32 + (lc >> 1);
        float rv[4];
#pragma unroll
        for (int n = 0; n < 4; ++n) {
          float2 cs = rp[n * 8];
          rv[n] = (n < 2) ? vv[n] * cs.x - vv[n + 2] * cs.y
                          : vv[n] * cs.x + vv[n - 2] * cs.y;
        }
#pragma unroll
        for (int n = 0; n < 4; ++n) vv[n] = rv[n];
      }
      const size_t cbase = grow * (size_t)DMODEL + ocol + lc;
      if constexpr (MODE == 1) {
#pragma unroll
        for (int n = 0; n < 4; ++n) Cf[cbase + n * 16] = vv[n];
      } else {
#pragma unroll
        for (int n = 0; n < 4; ++n) Cb[cbase + n * 16] = (bf16_t)vv[n];
      }
    }
  }
}

// ---------------- per-position head-mixing attention ----------------
__global__ __launch_bounds__(256) void attn_heads_k(const bf16_t* __restrict__ qb,
                                                    const bf16_t* __restrict__ kb,
                                                    const bf16_t* __restrict__ vb,
                                                    bf16_t* __restrict__ ob) {
  const int t = blockIdx.x * 256 + threadIdx.x;
  const int row = t >> 4;
  const int h = t & 15;
  const size_t rbase = (size_t)row * DMODEL;

  float q[HDIM];
#pragma unroll
  for (int j = 0; j < 8; ++j) {
    bf16x8 v8 = *(const bf16x8*)(qb + rbase + h * HDIM + j * 8);
#pragma unroll
    for (int u = 0; u < 8; ++u) q[j * 8 + u] = (float)v8[u];
  }
  float s[NHEAD];
#pragma unroll
  for (int e = 0; e < NHEAD; ++e) {
    float a = 0.f;
#pragma unroll
    for (int j = 0; j < 8; ++j) {
      bf16x8 k8 = *(const bf16x8*)(kb + rbase + e * HDIM + j * 8);
#pragma unroll
      for (int u = 0; u < 8; ++u) a += q[j * 8 + u] * (float)k8[u];
    }
    s[e] = a * 0.125f;
  }
  float mx = s[0];
#pragma unroll
  for (int e = 1; e < NHEAD; ++e) mx = fmaxf(mx, s[e]);
  float sum = 0.f;
#pragma unroll
  for (int e = 0; e < NHEAD; ++e) {
    s[e] = __expf(s[e] - mx);
    sum += s[e];
  }
  const float inv = 1.f / sum;
  float o[HDIM] = {};
#pragma unroll
  for (int e = 0; e < NHEAD; ++e) {
    const float w = s[e] * inv;
#pragma unroll
    for (int j = 0; j < 8; ++j) {
      bf16x8 v8 = *(const bf16x8*)(vb + rbase + e * HDIM + j * 8);
#pragma unroll
      for (int u = 0; u < 8; ++u) o[j * 8 + u] += w * (float)v8[u];
    }
  }
#pragma unroll
  for (int j = 0; j < 8; ++j) {
    bf16x8 st;
#pragma unroll
    for (int u = 0; u < 8; ++u) st[u] = (__bf16)o[j * 8 + u];
    *(bf16x8*)(ob + rbase + h * HDIM + j * 8) = st;
  }
}

extern "C" void kernel_launch(void* const* d_in, const int* in_sizes, int n_in,
                              void* d_out, int out_size, void* d_ws, size_t ws_size,
                              hipStream_t stream) {
  const float* x = (const float*)d_in[0];
  const float* Wq = (const float*)d_in[1];
  const float* bq = (const float*)d_in[2];
  const float* Wk = (const float*)d_in[3];
  const float* bk = (const float*)d_in[4];
  const float* Wv = (const float*)d_in[5];
  const float* bv = (const float*)d_in[6];
  const float* Wo = (const float*)d_in[7];
  const float* bo = (const float*)d_in[8];

  const int M = MROWS, N = DMODEL, K = DMODEL;

  char* p = (char*)d_ws;
  bf16_t* xb = (bf16_t*)p;    p += (size_t)M * K * 2;      // 32 MB
  bf16_t* Wqkvt = (bf16_t*)p; p += (size_t)3 * N * K * 2;  // 6 MB (q|k|v rows)
  bf16_t* Wot = (bf16_t*)p;   p += (size_t)N * K * 2;      // 2 MB
  bf16_t* qb = (bf16_t*)p;    p += (size_t)M * N * 2;      // 32 MB each
  bf16_t* kb = (bf16_t*)p;    p += (size_t)M * N * 2;
  bf16_t* vb = (bf16_t*)p;    p += (size_t)M * N * 2;
  bf16_t* ab = (bf16_t*)p;    p += (size_t)M * N * 2;
  float2* rope = (float2*)p;  p += (size_t)SEQ_L * 32 * sizeof(float2);  // 2 MB

  bf16_t* Wqt = Wqkvt;
  bf16_t* Wkt = Wqkvt + (size_t)N * K;
  bf16_t* Wvt = Wqkvt + (size_t)2 * N * K;

  f32_to_bf16_k<<<(M * K) / (256 * 8), 256, 0, stream>>>(x, xb, M * K);
  w_to_bt_k<<<dim3(32, 32, 4), dim3(32, 8), 0, stream>>>(Wq, Wk, Wv, Wo, Wqt, Wkt, Wvt, Wot);
  rope_tab_k<<<(SEQ_L * 32) / 256, 256, 0, stream>>>(rope);

  // fused QKV: C(16384 x 3072), 128 x 24 blocks of 128^2
  gemm128<0><<<dim3(M / 128, (3 * N) / 128), 256, 0, stream>>>(
      xb, Wqkvt, bq, bk, bv, rope, (void*)qb, (void*)kb, (void*)vb);
  attn_heads_k<<<(M * NHEAD) / 256, 256, 0, stream>>>(qb, kb, vb, ab);
  gemm128<1><<<dim3(M / 128, N / 128), 256, 0, stream>>>(
      ab, Wot, bo, nullptr, nullptr, nullptr, d_out, nullptr, nullptr);
}

// Round 16
// 222.615 us; speedup vs baseline: 1.1723x; 1.1723x over previous
//
#include <hip/hip_runtime.h>
#include <hip/hip_bf16.h>

typedef __bf16 bf16_t;
typedef __bf16 bf16x8 __attribute__((ext_vector_type(8)));
typedef float f32x4 __attribute__((ext_vector_type(4)));

#define SEQ_L 8192
#define DMODEL 1024
#define NHEAD 16
#define HDIM 64
static constexpr int MROWS = 2 * SEQ_L;  // B*L = 16384

// ---------------- async global->LDS (16B per lane) ----------------
__device__ __forceinline__ void async_cp16(const void* g, bf16_t* l) {
  __builtin_amdgcn_global_load_lds(
      (__attribute__((address_space(1))) void*)(void*)(g),
      (__attribute__((address_space(3))) void*)(void*)(l), 16, 0, 0);
}
// Raw barrier: does NOT drain vmcnt/lgkmcnt (waits are placed by hand).
__device__ __forceinline__ void wg_barrier() { __builtin_amdgcn_s_barrier(); }

// ------------- merged preamble: convert + weight-transpose + rope -------------
// blocks [0,8192):        f32->bf16 convert of x (256 thr x 8 elems)
// blocks [8192,12288):    W (KxN f32) -> Wt (NxK bf16), 32x32 tiles, 4 weights
// blocks [12288,13312):   RoPE cos/sin table tab[pos*32+j]
// Merging overlaps the BW-bound sections and removes two launch gaps.
__global__ __launch_bounds__(256) void prep_k(
    const float* __restrict__ x, bf16_t* __restrict__ xb,
    const float* __restrict__ W0, const float* __restrict__ W1,
    const float* __restrict__ W2, const float* __restrict__ W3,
    bf16_t* __restrict__ T0, bf16_t* __restrict__ T1,
    bf16_t* __restrict__ T2, bf16_t* __restrict__ T3,
    float2* __restrict__ tab) {
  __shared__ float tile[32][33];
  const int bid = blockIdx.x;
  const int tid = threadIdx.x;
  if (bid < 8192) {
    const int i = (bid * 256 + tid) * 8;
    float4 a = *(const float4*)(x + i);
    float4 b = *(const float4*)(x + i + 4);
    bf16x8 o;
    o[0] = (__bf16)a.x; o[1] = (__bf16)a.y; o[2] = (__bf16)a.z; o[3] = (__bf16)a.w;
    o[4] = (__bf16)b.x; o[5] = (__bf16)b.y; o[6] = (__bf16)b.z; o[7] = (__bf16)b.w;
    *(bf16x8*)(xb + i) = o;
  } else if (bid < 12288) {
    const int id2 = bid - 8192;
    const int z = id2 >> 10;
    const int by = (id2 & 1023) >> 5;
    const int bx = id2 & 31;
    const float* W = (z == 0) ? W0 : (z == 1) ? W1 : (z == 2) ? W2 : W3;
    bf16_t* T = (z == 0) ? T0 : (z == 1) ? T1 : (z == 2) ? T2 : T3;
    const int tx = tid & 31, ty = tid >> 5;  // 32 x 8
#pragma unroll
    for (int r = 0; r < 4; ++r)
      tile[ty + r * 8][tx] = W[(size_t)(by * 32 + ty + r * 8) * DMODEL + bx * 32 + tx];
    __syncthreads();
#pragma unroll
    for (int r = 0; r < 4; ++r)
      T[(size_t)(bx * 32 + ty + r * 8) * DMODEL + by * 32 + tx] = (bf16_t)tile[tx][ty + r * 8];
  } else {
    const int i = (bid - 12288) * 256 + tid;  // pos*32 + j
    const int pos = i >> 5, j = i & 31;
    double freq = pow(10000.0, -(double)j / 32.0);
    double ang = (double)pos * freq;
    tab[i] = make_float2((float)cos(ang), (float)sin(ang));
  }
}

// -- 256x128 bf16 GEMM, 128x64 per wave, BK=64 single-buffer, anti-phase (R14) --
// C(M x N) = A(M x K) @ Bt(N x K)^T + bias, K=1024, 4 waves (2M x 2N),
// per-wave 128x64 output (acc[8][4] = 128 AGPR; ~244 combined regs -> 2
// blocks/CU anti-phase).  Best measured GEMM of the session (885 TF, R14).
// Per K-tile: {reads kh0 (12 x ds_read_b128) + 32 MFMA, reads kh1 + 32 MFMA}
// -> lgkm0 -> barrier -> stage(m+1) (12 cp16, WAR-safe) -> vmcnt(0) -> barrier.
// Swizzle (measured 0-conflict): bf16 row 128B = 8 chunks; physical chunk =
// logical ^ (row&7); read applies XOR; write pre-swizzles the GLOBAL source
// chunk, LDS dest linear (global_load_lds requirement).
// MODE 0: fused QKV (N=3072), bias per range, RoPE on q/k, bf16 outs (stride 1024).
// MODE 1: f32 out + bias (O projection, N=1024).
template <int MODE>
__global__ __launch_bounds__(256, 2) void gemm256x128(
    const bf16_t* __restrict__ A, const bf16_t* __restrict__ Bt,
    const float* __restrict__ b0, const float* __restrict__ b1,
    const float* __restrict__ b2, const float2* __restrict__ rope,
    void* __restrict__ O0, void* __restrict__ O1, void* __restrict__ O2) {
  constexpr int K = DMODEL;   // 1024
  constexpr int KT = K / 64;  // 16 K-tiles (BK=64)
  __shared__ bf16_t As_[256 * 64];  // 32 KB
  __shared__ bf16_t Bs_[128 * 64];  // 16 KB
  const int tid = threadIdx.x;
  const int lane = tid & 63;
  const int wave = tid >> 6;  // 0..3
  const int wm = wave >> 1;   // 0..1 (128-row half)
  const int wn = wave & 1;    // 0..1 (64-col half)
  const size_t row0 = (size_t)blockIdx.x * 256;
  const int col0 = blockIdx.y * 128;
  const int fr = lane & 15;
  const int g4 = lane >> 4;  // 0..3: 16B k-chunk group

  // staging: thread covers rows (tid>>3) + 32c, physical chunk tid&7;
  // source chunk pre-swizzled by ((tid>>3)&7) == row&7 for all c (32c%8==0).
  const int srow = tid >> 3;                      // 0..31
  const int sch = (tid & 7) ^ ((tid >> 3) & 7);   // pre-swizzled source chunk
  const bf16_t* gA = A + (row0 + srow) * K + sch * 8;
  const bf16_t* gB = Bt + ((size_t)col0 + srow) * K + sch * 8;

#define VMCNT(n) asm volatile("s_waitcnt vmcnt(" #n ")")
#define LGKM0() asm volatile("s_waitcnt lgkmcnt(0)")
#define SCHED_FENCE() __builtin_amdgcn_sched_barrier(0)

  auto stage = [&](int j) {
#pragma unroll
    for (int c = 0; c < 8; ++c)  // A: 256 rows
      async_cp16(gA + (size_t)(32 * c) * K + j * 64, As_ + c * 2048 + tid * 8);
#pragma unroll
    for (int c = 0; c < 4; ++c)  // B: 128 rows
      async_cp16(gB + (size_t)(32 * c) * K + j * 64, Bs_ + c * 2048 + tid * 8);
  };
  auto read_a = [&](int f, int h) -> bf16x8 {
    const int R = wm * 128 + f * 16 + fr;
    return *(const bf16x8*)((const char*)As_ + (size_t)R * 128 +
                            (((h * 4 + g4) ^ (R & 7)) << 4));
  };
  auto read_b = [&](int n, int h) -> bf16x8 {
    const int R = wn * 64 + n * 16 + fr;
    return *(const bf16x8*)((const char*)Bs_ + (size_t)R * 128 +
                            (((h * 4 + g4) ^ (R & 7)) << 4));
  };

  f32x4 acc[8][4] = {};
  bf16x8 a8[8], b4[4];

  // prologue
  stage(0);
  VMCNT(0);
  wg_barrier();
  SCHED_FENCE();

  for (int m = 0; m < KT; ++m) {
#pragma unroll
    for (int h = 0; h < 2; ++h) {
#pragma unroll
      for (int f = 0; f < 8; ++f) a8[f] = read_a(f, h);
#pragma unroll
      for (int n = 0; n < 4; ++n) b4[n] = read_b(n, h);
      __builtin_amdgcn_s_setprio(1);
#pragma unroll
      for (int f = 0; f < 8; ++f)
#pragma unroll
        for (int n = 0; n < 4; ++n)
          acc[f][n] = __builtin_amdgcn_mfma_f32_16x16x32_bf16(a8[f], b4[n], acc[f][n], 0, 0, 0);
      __builtin_amdgcn_s_setprio(0);
    }
    // ---- tile boundary ----
    LGKM0();
    SCHED_FENCE();
    wg_barrier();  // all waves done reading tile m
    SCHED_FENCE();
    if (m + 1 < KT) stage(m + 1);  // WAR-safe overwrite
    VMCNT(0);                      // new tile landed
    wg_barrier();
    SCHED_FENCE();
  }
#undef VMCNT
#undef LGKM0
#undef SCHED_FENCE

  // ---- epilogue. C/D layout: col = lane&15, row = (lane>>4)*4 + reg ----
  const int lr = g4 * 4;
  const int lc = lane & 15;
  const int gcol = col0 + wn * 64;  // aligned to one head (64)
  int which = 0;
  const float* bias = b0;
  int ocol = gcol;
  if constexpr (MODE == 0) {
    which = gcol >> 10;
    bias = (which == 0) ? b0 : (which == 1) ? b1 : b2;
    ocol = gcol - (which << 10);
  }
  const bool do_rope = (MODE == 0) && (which < 2);
  bf16_t* Cb = nullptr;
  float* Cf = nullptr;
  if constexpr (MODE == 0)
    Cb = (bf16_t*)((which == 0) ? O0 : (which == 1) ? O1 : O2);
  else
    Cf = (float*)O0;

#pragma unroll
  for (int mf = 0; mf < 8; ++mf) {
#pragma unroll
    for (int i = 0; i < 4; ++i) {
      const size_t grow = row0 + wm * 128 + mf * 16 + lr + i;
      float vv[4];
#pragma unroll
      for (int n = 0; n < 4; ++n) vv[n] = acc[mf][n][i] + bias[ocol + n * 16 + lc];
      if (do_rope) {
        // d(in-head) = n*16+lc; j = d>>1; partner d<32 ? d+32 (-sin) : d-32 (+sin)
        const int pos = (int)(grow & (size_t)(SEQ_L - 1));
        const float2* rp = rope + (size_t)pos * 32 + (lc >> 1);
        float rv[4];
#pragma unroll
        for (int n = 0; n < 4; ++n) {
          float2 cs = rp[n * 8];
          rv[n] = (n < 2) ? vv[n] * cs.x - vv[n + 2] * cs.y
                          : vv[n] * cs.x + vv[n - 2] * cs.y;
        }
#pragma unroll
        for (int n = 0; n < 4; ++n) vv[n] = rv[n];
      }
      const size_t cbase = grow * (size_t)DMODEL + ocol + lc;
      if constexpr (MODE == 1) {
#pragma unroll
        for (int n = 0; n < 4; ++n) Cf[cbase + n * 16] = vv[n];
      } else {
#pragma unroll
        for (int n = 0; n < 4; ++n) Cb[cbase + n * 16] = (bf16_t)vv[n];
      }
    }
  }
}

// ---------------- per-position head-mixing attention ----------------
__global__ __launch_bounds__(256) void attn_heads_k(const bf16_t* __restrict__ qb,
                                                    const bf16_t* __restrict__ kb,
                                                    const bf16_t* __restrict__ vb,
                                                    bf16_t* __restrict__ ob) {
  const int t = blockIdx.x * 256 + threadIdx.x;
  const int row = t >> 4;
  const int h = t & 15;
  const size_t rbase = (size_t)row * DMODEL;

  float q[HDIM];
#pragma unroll
  for (int j = 0; j < 8; ++j) {
    bf16x8 v8 = *(const bf16x8*)(qb + rbase + h * HDIM + j * 8);
#pragma unroll
    for (int u = 0; u < 8; ++u) q[j * 8 + u] = (float)v8[u];
  }
  float s[NHEAD];
#pragma unroll
  for (int e = 0; e < NHEAD; ++e) {
    float a = 0.f;
#pragma unroll
    for (int j = 0; j < 8; ++j) {
      bf16x8 k8 = *(const bf16x8*)(kb + rbase + e * HDIM + j * 8);
#pragma unroll
      for (int u = 0; u < 8; ++u) a += q[j * 8 + u] * (float)k8[u];
    }
    s[e] = a * 0.125f;
  }
  float mx = s[0];
#pragma unroll
  for (int e = 1; e < NHEAD; ++e) mx = fmaxf(mx, s[e]);
  float sum = 0.f;
#pragma unroll
  for (int e = 0; e < NHEAD; ++e) {
    s[e] = __expf(s[e] - mx);
    sum += s[e];
  }
  const float inv = 1.f / sum;
  float o[HDIM] = {};
#pragma unroll
  for (int e = 0; e < NHEAD; ++e) {
    const float w = s[e] * inv;
#pragma unroll
    for (int j = 0; j < 8; ++j) {
      bf16x8 v8 = *(const bf16x8*)(vb + rbase + e * HDIM + j * 8);
#pragma unroll
      for (int u = 0; u < 8; ++u) o[j * 8 + u] += w * (float)v8[u];
    }
  }
#pragma unroll
  for (int j = 0; j < 8; ++j) {
    bf16x8 st;
#pragma unroll
    for (int u = 0; u < 8; ++u) st[u] = (__bf16)o[j * 8 + u];
    *(bf16x8*)(ob + rbase + h * HDIM + j * 8) = st;
  }
}

extern "C" void kernel_launch(void* const* d_in, const int* in_sizes, int n_in,
                              void* d_out, int out_size, void* d_ws, size_t ws_size,
                              hipStream_t stream) {
  const float* x = (const float*)d_in[0];
  const float* Wq = (const float*)d_in[1];
  const float* bq = (const float*)d_in[2];
  const float* Wk = (const float*)d_in[3];
  const float* bk = (const float*)d_in[4];
  const float* Wv = (const float*)d_in[5];
  const float* bv = (const float*)d_in[6];
  const float* Wo = (const float*)d_in[7];
  const float* bo = (const float*)d_in[8];

  const int M = MROWS, N = DMODEL, K = DMODEL;

  char* p = (char*)d_ws;
  bf16_t* xb = (bf16_t*)p;    p += (size_t)M * K * 2;      // 32 MB
  bf16_t* Wqkvt = (bf16_t*)p; p += (size_t)3 * N * K * 2;  // 6 MB (q|k|v rows)
  bf16_t* Wot = (bf16_t*)p;   p += (size_t)N * K * 2;      // 2 MB
  bf16_t* qb = (bf16_t*)p;    p += (size_t)M * N * 2;      // 32 MB each
  bf16_t* kb = (bf16_t*)p;    p += (size_t)M * N * 2;
  bf16_t* vb = (bf16_t*)p;    p += (size_t)M * N * 2;
  bf16_t* ab = (bf16_t*)p;    p += (size_t)M * N * 2;
  float2* rope = (float2*)p;  p += (size_t)SEQ_L * 32 * sizeof(float2);  // 2 MB

  bf16_t* Wqt = Wqkvt;
  bf16_t* Wkt = Wqkvt + (size_t)N * K;
  bf16_t* Wvt = Wqkvt + (size_t)2 * N * K;

  // merged preamble: convert (8192) + w-transpose (4096) + rope (1024)
  prep_k<<<13312, 256, 0, stream>>>(x, xb, Wq, Wk, Wv, Wo, Wqt, Wkt, Wvt, Wot, rope);

  // fused QKV: C(16384 x 3072), 64 x 24 blocks of 256x128
  gemm256x128<0><<<dim3(M / 256, (3 * N) / 128), 256, 0, stream>>>(
      xb, Wqkvt, bq, bk, bv, rope, (void*)qb, (void*)kb, (void*)vb);
  attn_heads_k<<<(M * NHEAD) / 256, 256, 0, stream>>>(qb, kb, vb, ab);
  gemm256x128<1><<<dim3(M / 256, N / 128), 256, 0, stream>>>(
      ab, Wot, bo, nullptr, nullptr, nullptr, d_out, nullptr, nullptr);
}